// Round 1
// baseline (334.933 us; speedup 1.0000x reference)
//
#include <hip/hip_runtime.h>

// WindowAttention fused kernel for MI355X (gfx950).
// Shapes: B_=4096 windows, N=64 tokens, DIM=128, NH=4 heads, HD=32, nW=64.
// One block per window, one wave per head. bf16 MFMA (32x32x16), fp32 accum.

typedef __bf16 bf16x8 __attribute__((ext_vector_type(8)));
typedef float f32x16 __attribute__((ext_vector_type(16)));

#define MFMA32(a, b, c) __builtin_amdgcn_mfma_f32_32x32x16_bf16(a, b, c, 0, 0, 0)
#define ATT_SCALE 0.17677669529663687f  // 32^-0.5

__device__ __forceinline__ unsigned short f2bf(float f) {
  union { float fv; unsigned int u; } cv; cv.fv = f;
  unsigned int r = cv.u + 0x7FFFu + ((cv.u >> 16) & 1u);  // RNE truncate
  return (unsigned short)(r >> 16);
}

// ---- pre-kernel 1: fp32 weights -> bf16 in workspace ----
__global__ __launch_bounds__(256) void convert_weights(
    const float* __restrict__ qkv_w, const float* __restrict__ proj_w,
    unsigned short* __restrict__ wq, unsigned short* __restrict__ wp) {
  int t = blockIdx.x * 256 + threadIdx.x;  // 65536 total = 49152 + 16384
  if (t < 384 * 128) wq[t] = f2bf(qkv_w[t]);
  else               wp[t - 384 * 128] = f2bf(proj_w[t - 384 * 128]);
}

// ---- pre-kernel 2: combined bias CB[w][h][i][j] = rel_bias[h][i][j] + mask[w][i][j] ----
__global__ __launch_bounds__(256) void build_cb(
    const float* __restrict__ mask, const float* __restrict__ bias_table,
    float* __restrict__ cb) {
  int t = blockIdx.x * 256 + threadIdx.x;  // nW*4*4096 total
  int ij = t & 4095;
  int h = (t >> 12) & 3;
  int w = t >> 14;
  int i = ij >> 6, j = ij & 63;
  int ridx = ((i >> 3) - (j >> 3) + 7) * 15 + ((i & 7) - (j & 7) + 7);
  cb[t] = bias_table[ridx * 4 + h] + mask[(w << 12) + ij];
}

// ---- fused window attention ----
__global__ __launch_bounds__(256, 2) void window_attn(
    const float* __restrict__ x, const float* __restrict__ qkv_b,
    const float* __restrict__ proj_b, const unsigned short* __restrict__ wq,
    const unsigned short* __restrict__ wp, const float* __restrict__ cb,
    float* __restrict__ out, int nW) {
  // Xb: x in bf16, stride 136 (16B-aligned rows); reused as O (heads concat) later.
  __shared__ unsigned short Xb[64][136];                 // 17408 B
  // Per-head union region (private to wave h):
  //  phase A: q[64][40] @0, k[64][40] @2560, vT[32][72] @5120   (14848 B)
  //  phase B: P[64][72] @0 (overwrites q/k after S reads), vT kept @5120
  __shared__ unsigned short U[4][7424];                  // 59392 B  (total 76800)

  const int tid = threadIdx.x;
  const int h = tid >> 6;          // wave index == head
  const int lane = tid & 63;
  const int l31 = lane & 31;
  const int hl = lane >> 5;        // wave half (selects k-block of MFMA fragment)
  const int b = blockIdx.x;
  const int w = b % nW;

  // ---- stage x[b] (64x128 fp32) -> bf16 LDS, coalesced float4 ----
  const float* xb = x + (size_t)b * 8192;
  #pragma unroll
  for (int it = 0; it < 8; ++it) {
    int e = (it * 256 + tid) * 4;
    float4 v = *reinterpret_cast<const float4*>(xb + e);
    ushort4 o;
    o.x = f2bf(v.x); o.y = f2bf(v.y); o.z = f2bf(v.z); o.w = f2bf(v.w);
    *reinterpret_cast<ushort4*>(&Xb[e >> 7][e & 127]) = o;
  }
  __syncthreads();

  unsigned short* qh = &U[h][0];      // [64][40]
  unsigned short* kh = &U[h][2560];   // [64][40]
  unsigned short* vh = &U[h][5120];   // [32][72]  (v transposed: vT[d][j])
  unsigned short* ph = &U[h][0];      // [64][72]

  // ---- QKV projection: wave h computes channels {s*128 + h*32 .. +31}, s=q,k,v ----
  #pragma unroll
  for (int s = 0; s < 3; ++s) {
    const int c = s * 128 + h * 32 + l31;
    const float bias = qkv_b[c];
    const unsigned short* wrow = wq + (size_t)c * 128 + hl * 8;
    bf16x8 bfr[8];
    #pragma unroll
    for (int kt = 0; kt < 8; ++kt)
      bfr[kt] = *reinterpret_cast<const bf16x8*>(wrow + kt * 16);  // B[k][n]=W[c][k]
    #pragma unroll
    for (int mt = 0; mt < 2; ++mt) {
      f32x16 acc;
      #pragma unroll
      for (int q = 0; q < 16; ++q) acc[q] = 0.0f;
      #pragma unroll
      for (int kt = 0; kt < 8; ++kt) {
        bf16x8 a = *reinterpret_cast<const bf16x8*>(&Xb[mt * 32 + l31][kt * 16 + hl * 8]);
        acc = MFMA32(a, bfr[kt], acc);
      }
      #pragma unroll
      for (int r = 0; r < 16; ++r) {
        int row = (r & 3) + 8 * (r >> 2) + 4 * hl + mt * 32;  // C/D layout (m74/m101)
        float val = acc[r] + bias;
        if (s == 0)      qh[row * 40 + l31] = f2bf(val * ATT_SCALE);
        else if (s == 1) kh[row * 40 + l31] = f2bf(val);
        else             vh[l31 * 72 + row] = f2bf(val);       // transpose
      }
    }
  }
  __syncthreads();  // everyone done reading Xb -> safe to reuse as O

  // ---- S = q k^T  (A=q[i][d], B[d][j]=k[j][d] read row-major from k) ----
  f32x16 sacc[2][2];
  #pragma unroll
  for (int mt = 0; mt < 2; ++mt)
    #pragma unroll
    for (int jt = 0; jt < 2; ++jt)
      #pragma unroll
      for (int q = 0; q < 16; ++q) sacc[mt][jt][q] = 0.0f;
  #pragma unroll
  for (int kt = 0; kt < 2; ++kt) {
    bf16x8 b0 = *reinterpret_cast<const bf16x8*>(&kh[(l31) * 40 + kt * 16 + hl * 8]);
    bf16x8 b1 = *reinterpret_cast<const bf16x8*>(&kh[(32 + l31) * 40 + kt * 16 + hl * 8]);
    #pragma unroll
    for (int mt = 0; mt < 2; ++mt) {
      bf16x8 a = *reinterpret_cast<const bf16x8*>(&qh[(mt * 32 + l31) * 40 + kt * 16 + hl * 8]);
      sacc[mt][0] = MFMA32(a, b0, sacc[mt][0]);
      sacc[mt][1] = MFMA32(a, b1, sacc[mt][1]);
    }
  }

  // ---- softmax over rows (register reduce across the 32-lane half that owns the row) ----
  const float* cbp = cb + (((size_t)w * 4 + h) << 12);
  float rinv[2][16];
  #pragma unroll
  for (int mt = 0; mt < 2; ++mt) {
    #pragma unroll
    for (int r = 0; r < 16; ++r) {
      int row = (r & 3) + 8 * (r >> 2) + 4 * hl + mt * 32;
      float s0 = sacc[mt][0][r] + cbp[row * 64 + l31];
      float s1 = sacc[mt][1][r] + cbp[row * 64 + 32 + l31];
      float m = fmaxf(s0, s1);
      m = fmaxf(m, __shfl_xor(m, 1));
      m = fmaxf(m, __shfl_xor(m, 2));
      m = fmaxf(m, __shfl_xor(m, 4));
      m = fmaxf(m, __shfl_xor(m, 8));
      m = fmaxf(m, __shfl_xor(m, 16));
      float e0 = __expf(s0 - m);
      float e1 = __expf(s1 - m);
      float sum = e0 + e1;
      sum += __shfl_xor(sum, 1);
      sum += __shfl_xor(sum, 2);
      sum += __shfl_xor(sum, 4);
      sum += __shfl_xor(sum, 8);
      sum += __shfl_xor(sum, 16);
      ph[row * 72 + l31] = f2bf(e0);        // unnormalized P; divide after PV
      ph[row * 72 + 32 + l31] = f2bf(e1);
      rinv[mt][r] = __builtin_amdgcn_rcpf(sum);  // same lanes own these rows in O
    }
  }

  // ---- O_h = P v  (A=P[i][j], B[j][d]=v[j][d]=vT[d][j] read row-major from vT) ----
  #pragma unroll
  for (int mt = 0; mt < 2; ++mt) {
    f32x16 oacc;
    #pragma unroll
    for (int q = 0; q < 16; ++q) oacc[q] = 0.0f;
    #pragma unroll
    for (int kt = 0; kt < 4; ++kt) {
      bf16x8 a = *reinterpret_cast<const bf16x8*>(&ph[(mt * 32 + l31) * 72 + kt * 16 + hl * 8]);
      bf16x8 bb = *reinterpret_cast<const bf16x8*>(&vh[l31 * 72 + kt * 16 + hl * 8]);
      oacc = MFMA32(a, bb, oacc);
    }
    #pragma unroll
    for (int r = 0; r < 16; ++r) {
      int row = (r & 3) + 8 * (r >> 2) + 4 * hl + mt * 32;
      Xb[row][h * 32 + l31] = f2bf(oacc[r] * rinv[mt][r]);  // Xb reused as O
    }
  }
  __syncthreads();  // O (all heads) ready

  // ---- out = O proj_w^T + proj_b : wave h computes out channels [h*32, h*32+32) ----
  {
    const int c = h * 32 + l31;
    const float pb = proj_b[c];
    const unsigned short* wrow = wp + (size_t)c * 128 + hl * 8;
    bf16x8 bfr[8];
    #pragma unroll
    for (int kt = 0; kt < 8; ++kt)
      bfr[kt] = *reinterpret_cast<const bf16x8*>(wrow + kt * 16);
    float* ob = out + (size_t)b * 8192;
    #pragma unroll
    for (int mt = 0; mt < 2; ++mt) {
      f32x16 acc;
      #pragma unroll
      for (int q = 0; q < 16; ++q) acc[q] = 0.0f;
      #pragma unroll
      for (int kt = 0; kt < 8; ++kt) {
        bf16x8 a = *reinterpret_cast<const bf16x8*>(&Xb[mt * 32 + l31][kt * 16 + hl * 8]);
        acc = MFMA32(a, bfr[kt], acc);
      }
      #pragma unroll
      for (int r = 0; r < 16; ++r) {
        int row = (r & 3) + 8 * (r >> 2) + 4 * hl + mt * 32;
        ob[row * 128 + c] = acc[r] + pb;  // fp32 out, coalesced per 32-lane group
      }
    }
  }
}

extern "C" void kernel_launch(void* const* d_in, const int* in_sizes, int n_in,
                              void* d_out, int out_size, void* d_ws, size_t ws_size,
                              hipStream_t stream) {
  const float* x          = (const float*)d_in[0];
  const float* mask       = (const float*)d_in[1];
  const float* qkv_w      = (const float*)d_in[2];
  const float* qkv_b      = (const float*)d_in[3];
  const float* proj_w     = (const float*)d_in[4];
  const float* proj_b     = (const float*)d_in[5];
  const float* bias_table = (const float*)d_in[6];
  const int B_ = in_sizes[0] / 8192;   // 4096
  const int nW = in_sizes[1] / 4096;   // 64

  // workspace carve: wq bf16 (98304 B) | wp bf16 (32768 B) | CB fp32 (nW*4*4096*4 B)
  unsigned short* wq = (unsigned short*)d_ws;
  unsigned short* wp = wq + 384 * 128;
  float* cbuf = (float*)((char*)d_ws + 131072);

  convert_weights<<<(384 * 128 + 128 * 128) / 256, 256, 0, stream>>>(qkv_w, proj_w, wq, wp);
  build_cb<<<(nW * 4 * 4096) / 256, 256, 0, stream>>>(mask, bias_table, cbuf);
  window_attn<<<B_, 256, 0, stream>>>(x, qkv_b, proj_b, wq, wp, cbuf, (float*)d_out, nW);
}